// Round 14
// baseline (256.950 us; speedup 1.0000x reference)
//
#include <hip/hip_runtime.h>
#include <hip/hip_bf16.h>
#include <cstdint>
#include <cstddef>

typedef __bf16 bf16x8 __attribute__((ext_vector_type(8)));
typedef float f32x4 __attribute__((ext_vector_type(4)));
using u16 = unsigned short;

#define NUM_GROUPS_C 2048

__device__ __forceinline__ u16 f2bf(float f) {
  union { float f; uint32_t u; } c; c.f = f;
  uint32_t r = (c.u + 0x7fffu + ((c.u >> 16) & 1u)) >> 16;
  return (u16)r;
}
__device__ __forceinline__ float bf2f(u16 h) {
  union { uint32_t u; float f; } c; c.u = ((uint32_t)h) << 16; return c.f;
}

__device__ __forceinline__ void glds16(const u16* g, void* l) {
  __builtin_amdgcn_global_load_lds((const __attribute__((address_space(1))) void*)g,
                                   (__attribute__((address_space(3))) void*)l, 16, 0, 0);
}

// ---------------- cast fp32 -> bf16, vectorized ----------------
__global__ void cast_f32_bf16(const float* __restrict__ src, u16* __restrict__ dst, long n4) {
  long i = (long)blockIdx.x * blockDim.x + threadIdx.x;
  long stride = (long)gridDim.x * blockDim.x;
  for (; i < n4; i += stride) {
    float4 v = reinterpret_cast<const float4*>(src)[i];
    uint2 o;
    o.x = (uint32_t)f2bf(v.x) | ((uint32_t)f2bf(v.y) << 16);
    o.y = (uint32_t)f2bf(v.z) | ((uint32_t)f2bf(v.w) << 16);
    reinterpret_cast<uint2*>(dst)[i] = o;
  }
}

// ---------------- cast 3 weight matrices fp32 -> bf16 (one launch) ----------------
__global__ void cast_w3(const float* __restrict__ w0, const float* __restrict__ w1,
                        const float* __restrict__ w2,
                        u16* __restrict__ o0, u16* __restrict__ o1, u16* __restrict__ o2,
                        int n4) {
  const float* src = (blockIdx.y == 0) ? w0 : (blockIdx.y == 1) ? w1 : w2;
  u16* dst = (blockIdx.y == 0) ? o0 : (blockIdx.y == 1) ? o1 : o2;
  int i = blockIdx.x * blockDim.x + threadIdx.x;
  int stride = gridDim.x * blockDim.x;
  for (; i < n4; i += stride) {
    float4 v = reinterpret_cast<const float4*>(src)[i];
    uint2 o;
    o.x = (uint32_t)f2bf(v.x) | ((uint32_t)f2bf(v.y) << 16);
    o.y = (uint32_t)f2bf(v.z) | ((uint32_t)f2bf(v.w) << 16);
    reinterpret_cast<uint2*>(dst)[i] = o;
  }
}

// ---------------- bucket edges by group ----------------
__global__ void zero_i32(int* p, int n) {
  int i = blockIdx.x * blockDim.x + threadIdx.x;
  if (i < n) p[i] = 0;
}
__global__ void count_k(const int* __restrict__ ix, int* __restrict__ cnt, int E) {
  int e = blockIdx.x * blockDim.x + threadIdx.x;
  if (e < E) atomicAdd(&cnt[ix[e]], 1);
}
__global__ void scan_k(const int* __restrict__ cnt, int* __restrict__ offs,
                       int* __restrict__ cursor, int G) {
  __shared__ int part[256];
  int t = threadIdx.x;
  int gpt = G / 256;
  int base = t * gpt;
  int loc[8];
  int s = 0;
  for (int j = 0; j < gpt; ++j) { loc[j] = cnt[base + j]; s += loc[j]; }
  part[t] = s;
  __syncthreads();
  for (int off = 1; off < 256; off <<= 1) {
    int v = (t >= off) ? part[t - off] : 0;
    __syncthreads();
    part[t] += v;
    __syncthreads();
  }
  int run = part[t] - s;
  for (int j = 0; j < gpt; ++j) {
    offs[base + j] = run;
    cursor[base + j] = run;
    run += loc[j];
  }
}
__global__ void scatter_k(const int* __restrict__ ix, int* __restrict__ cursor,
                          int* __restrict__ elist, int E) {
  int e = blockIdx.x * blockDim.x + threadIdx.x;
  if (e < E) {
    int g = ix[e];
    int pos = atomicAdd(&cursor[g], 1);
    elist[pos] = e;
  }
}

// ===== f/g GEMM: R10's 4-phase schedule, 16 WAVES (1024 thr), per-wave 64x64 output =====
// Parameter-only change vs R10 (WARPS 2x4 -> 4x4): same phase map, same swizzle, same
// barrier placement. 4 waves/SIMD (vs 2) to hide per-phase stalls.
// Staging: one glds16 per thread per half-tile (1024 x 16B = 16 KB) -> vmcnt units halve:
//   prologue vmcnt(2); each phase stages 1 unit then vmcnt(2).
// Queue trace (per wave, in-order): invariant entering ph0(kt): {B1(kt),A1(kt)}=2.
//   ph0 +B0(kt+1)=3, vm(2) retires B1(kt) [read ph1]; ph1 +A0(kt+1)=3, vm(2) retires
//   A1(kt) [read ph2]; ph2 +B1(kt+1)=3, vm(2) retires B0(kt+1) [read ph0 next];
//   ph3 +A1(kt+1)=3, vm(2) retires A0(kt+1) [read ph0 next] -> invariant. Every region's
//   retire+barrier precedes its read; stage-over-read slots >=2 barriers apart (B0:
//   read ph0(kt-1) / staged ph0(kt), etc.). Tail: clamped restage into dead buffer.
// Frag rows: A mi*64+wm*16+fr (mi>>1 = half), B nj*64+wn*16+fr; row===fr (mod 8) so the
// read-side swizzle key swr=fr&7 is unchanged -> conflict-free as measured in R10/R13.
__global__ __launch_bounds__(1024, 1)
void gemm256_w16(const u16* __restrict__ A,
                 const u16* __restrict__ B0g, const u16* __restrict__ B1g,
                 const float* __restrict__ bias0, const float* __restrict__ bias1,
                 u16* __restrict__ C0, u16* __restrict__ C1,
                 int K, int N) {
  __shared__ u16 lds[65536];   // 2 bufs x (A 32KB + B 32KB) = 128 KiB

  const int tid  = threadIdx.x;
  const int lane = tid & 63;
  const int wid  = tid >> 6;   // 0..15
  const int wm   = wid >> 2;   // 0..3
  const int wn   = wid & 3;    // 0..3
  const int fr   = lane & 15;
  const int fq   = lane >> 4;
  const int swr  = fr & 7;

  // bijective XCD swizzle; ns fastest within mt for A-panel L2 reuse
  const int nwg = gridDim.x, cpx = nwg >> 3, wg = blockIdx.x;
  const int swz = (wg & 7) * cpx + (wg >> 3);
  const int mt = swz >> 2, ns = swz & 3;
  const u16* Bm     = (ns < 2) ? B0g : B1g;
  const float* bias = (ns < 2) ? bias0 : bias1;
  u16* C            = (ns < 2) ? C0 : C1;
  const int n0 = (ns & 1) * 256, m0 = mt * 256;

  const int r8   = tid >> 3;                      // 0..127: row within half-tile
  const int scol = ((tid & 7) ^ (r8 & 7)) << 3;   // pre-swizzled source column
  const u16* Ab = A  + (size_t)m0 * K + scol;
  const u16* Bb = Bm + (size_t)n0 * K + scol;
  char* ldsb = (char*)lds;

  auto stage_ht = [&](int p, int isB, int h, int kt) {
    const u16* src = (isB ? Bb : Ab) + (size_t)(h * 128 + r8) * K + kt * 64;
    char* dst = ldsb + p * 65536 + isB * 32768 + h * 16384 + wid * 1024;
    glds16(src, dst);                              // ONE load per thread (16 KB total)
  };

#define RD2_A(dst, mio)                                                             \
  _Pragma("unroll") for (int j = 0; j < 2; ++j)                                     \
  _Pragma("unroll") for (int kk = 0; kk < 2; ++kk)                                  \
    dst[j][kk] = *(const bf16x8*)(sA_ + ((((mio) + j) * 64 + wm * 16 + fr) << 7)    \
                                       + ((((kk << 2) | fq) ^ swr) << 4));
#define RD2_B(dst, njo)                                                             \
  _Pragma("unroll") for (int j = 0; j < 2; ++j)                                     \
  _Pragma("unroll") for (int kk = 0; kk < 2; ++kk)                                  \
    dst[j][kk] = *(const bf16x8*)(sB_ + ((((njo) + j) * 64 + wn * 16 + fr) << 7)    \
                                       + ((((kk << 2) | fq) ^ swr) << 4));
#define MFMA_Q(qm_, qn_, af, bf_)                                                  \
  __builtin_amdgcn_s_setprio(1);                                                  \
  _Pragma("unroll") for (int j = 0; j < 2; ++j)                                    \
  _Pragma("unroll") for (int jn = 0; jn < 2; ++jn)                                 \
  _Pragma("unroll") for (int kk = 0; kk < 2; ++kk)                                 \
    acc[(qm_) * 2 + j][(qn_) * 2 + jn] = __builtin_amdgcn_mfma_f32_16x16x32_bf16(  \
        af[j][kk], bf_[jn][kk], acc[(qm_) * 2 + j][(qn_) * 2 + jn], 0, 0, 0);      \
  __builtin_amdgcn_s_setprio(0);

  f32x4 acc[4][4] = {};
  const int NT = K >> 6;

  // prologue: K-tile 0 halves [B0, A0, B1, A1] into buf 0; retire B0,A0 before ph0 reads
  stage_ht(0, 1, 0, 0);
  stage_ht(0, 0, 0, 0);
  stage_ht(0, 1, 1, 0);
  stage_ht(0, 0, 1, 0);
  asm volatile("s_waitcnt vmcnt(2)" ::: "memory");
  __builtin_amdgcn_s_barrier();

  for (int kt = 0; kt < NT; ++kt) {
    const int cb = kt & 1, nb = cb ^ 1;
    const int ks = (kt + 1 < NT) ? kt + 1 : NT - 1;  // tail: redundant restage (dead buffer)
    const char* sA_ = ldsb + cb * 65536;
    const char* sB_ = sA_ + 32768;
    bf16x8 a0[2][2], a1[2][2], b0[2][2], b1[2][2];

    // ---- phase 0: read A-half0 + B-half0, MFMA quadrant (0,0) ----
    RD2_A(a0, 0)
    RD2_B(b0, 0)
    stage_ht(nb, 1, 0, ks);                              // B0(kt+1)
    asm volatile("s_waitcnt vmcnt(2)" ::: "memory");
    __builtin_amdgcn_s_barrier();
    MFMA_Q(0, 0, a0, b0)
    __builtin_amdgcn_s_barrier();

    // ---- phase 1: read B-half1, MFMA (0,1) ----
    RD2_B(b1, 2)
    stage_ht(nb, 0, 0, ks);                              // A0(kt+1)
    asm volatile("s_waitcnt vmcnt(2)" ::: "memory");
    __builtin_amdgcn_s_barrier();
    MFMA_Q(0, 1, a0, b1)
    __builtin_amdgcn_s_barrier();

    // ---- phase 2: read A-half1, MFMA (1,1) ----
    RD2_A(a1, 2)
    stage_ht(nb, 1, 1, ks);                              // B1(kt+1)
    asm volatile("s_waitcnt vmcnt(2)" ::: "memory");
    __builtin_amdgcn_s_barrier();
    MFMA_Q(1, 1, a1, b1)
    __builtin_amdgcn_s_barrier();

    // ---- phase 3: no LDS reads, MFMA (1,0) ----
    stage_ht(nb, 0, 1, ks);                              // A1(kt+1)
    asm volatile("s_waitcnt vmcnt(2)" ::: "memory");
    __builtin_amdgcn_s_barrier();
    MFMA_Q(1, 0, a1, b0)
    __builtin_amdgcn_s_barrier();
  }
  asm volatile("s_waitcnt vmcnt(0)" ::: "memory");       // retire tail restage DMA

  // epilogue: C/D layout col=lane&15, row=(lane>>4)*4+r
  #pragma unroll
  for (int mi = 0; mi < 4; ++mi) {
    const int row = m0 + mi * 64 + wm * 16 + fq * 4;
    #pragma unroll
    for (int ni = 0; ni < 4; ++ni) {
      const int col = n0 + ni * 64 + wn * 16 + fr;
      const float bvv = bias[col];
      #pragma unroll
      for (int r = 0; r < 4; ++r)
        C[(size_t)(row + r) * N + col] = f2bf(acc[mi][ni][r] + bvv);
    }
  }
#undef RD2_A
#undef RD2_B
#undef MFMA_Q
}

// ---------------- 128x128 m97-structure GEMM (small h projection) ----------------
__device__ __forceinline__ void stage_tile_128x64(const u16* __restrict__ src, int ld,
                                                  u16* lds, int tid) {
  int wid = tid >> 6;
  #pragma unroll
  for (int i = 0; i < 4; ++i) {
    int c = i * 256 + tid;
    const u16* g = src + (size_t)(c >> 3) * ld + ((c & 7) << 3);
    char* l = (char*)lds + ((i * 4 + wid) << 10);
    glds16(g, l);
  }
}

__global__ __launch_bounds__(256)
void gemm_bf16_nt_f32out(const u16* __restrict__ A, const u16* __restrict__ Bm,
                         const float* __restrict__ bias,
                         float* __restrict__ C, int K, int N) {
  __shared__ u16 sA[128 * 64];
  __shared__ u16 sB[128 * 64];

  int tid = threadIdx.x;
  const int m0 = blockIdx.x * 128, n0 = blockIdx.y * 128;
  const u16* Ap = A + (size_t)m0 * K;
  const u16* Bp = Bm + (size_t)n0 * K;

  int lane = tid & 63;
  int wid = tid >> 6;
  int wm = wid >> 1, wn = wid & 1;
  int fr = lane & 15;
  int fq = lane >> 4;

  f32x4 acc[4][4] = {};

  for (int k0 = 0; k0 < K; k0 += 64) {
    stage_tile_128x64(Ap + k0, K, sA, tid);
    stage_tile_128x64(Bp + k0, K, sB, tid);
    __syncthreads();
    #pragma unroll
    for (int kk = 0; kk < 2; ++kk) {
      bf16x8 af[4], bfrag[4];
      #pragma unroll
      for (int mi = 0; mi < 4; ++mi)
        af[mi] = *reinterpret_cast<const bf16x8*>(&sA[(wm * 64 + mi * 16 + fr) * 64 + kk * 32 + fq * 8]);
      #pragma unroll
      for (int nj = 0; nj < 4; ++nj)
        bfrag[nj] = *reinterpret_cast<const bf16x8*>(&sB[(wn * 64 + nj * 16 + fr) * 64 + kk * 32 + fq * 8]);
      #pragma unroll
      for (int mi = 0; mi < 4; ++mi)
        #pragma unroll
        for (int nj = 0; nj < 4; ++nj)
          acc[mi][nj] = __builtin_amdgcn_mfma_f32_16x16x32_bf16(af[mi], bfrag[nj], acc[mi][nj], 0, 0, 0);
    }
    __syncthreads();
  }

  #pragma unroll
  for (int nj = 0; nj < 4; ++nj) {
    int col = n0 + wn * 64 + nj * 16 + fr;
    float bv = bias[col];
    #pragma unroll
    for (int mi = 0; mi < 4; ++mi) {
      int rowb = m0 + wm * 64 + mi * 16 + fq * 4;
      #pragma unroll
      for (int r = 0; r < 4; ++r)
        C[(size_t)(rowb + r) * N + col] = acc[mi][nj][r] + bv;
    }
  }
}

// ---------------- group-wise online softmax + weighted sum ----------------
__global__ __launch_bounds__(256)
void seg_softmax(const u16* __restrict__ lg, const u16* __restrict__ vl,
                 const int* __restrict__ cnt, const int* __restrict__ offs,
                 const int* __restrict__ elist,
                 u16* __restrict__ y, int E, int D, int B, int G) {
  __shared__ int eids[256];
  int g = blockIdx.x / B;
  int b = blockIdx.x - g * B;
  int t = threadIdx.x;
  int n = cnt[g], start = offs[g];
  int d0 = t * 2;

  float m0 = -1e30f, m1 = -1e30f, s0 = 0.f, s1 = 0.f, a0 = 0.f, a1 = 0.f;
  for (int c0 = 0; c0 < n; c0 += 256) {
    int nc = n - c0; if (nc > 256) nc = 256;
    __syncthreads();
    if (t < nc) eids[t] = elist[start + c0 + t];
    __syncthreads();
    for (int i = 0; i < nc; ++i) {
      size_t base = ((size_t)b * E + eids[i]) * D + d0;
      uint32_t lu = *reinterpret_cast<const uint32_t*>(lg + base);
      uint32_t vu = *reinterpret_cast<const uint32_t*>(vl + base);
      float l0 = bf2f((u16)(lu & 0xffffu)), l1 = bf2f((u16)(lu >> 16));
      float v0 = bf2f((u16)(vu & 0xffffu)), v1 = bf2f((u16)(vu >> 16));
      float nm0 = fmaxf(m0, l0);
      float sc0 = __expf(m0 - nm0), w0 = __expf(l0 - nm0);
      s0 = s0 * sc0 + w0; a0 = a0 * sc0 + w0 * v0; m0 = nm0;
      float nm1 = fmaxf(m1, l1);
      float sc1 = __expf(m1 - nm1), w1 = __expf(l1 - nm1);
      s1 = s1 * sc1 + w1; a1 = a1 * sc1 + w1 * v1; m1 = nm1;
    }
  }
  float r0 = (n > 0) ? a0 / s0 : 0.f;
  float r1 = (n > 0) ? a1 / s1 : 0.f;
  size_t yoff = ((size_t)b * G + g) * D + d0;
  uint32_t o = (uint32_t)f2bf(r0) | ((uint32_t)f2bf(r1) << 16);
  *reinterpret_cast<uint32_t*>(y + yoff) = o;
}

// ---------------- gather rows back to edges (fp32 out), grid-stride ----------------
__global__ __launch_bounds__(256)
void gather_k(const float* __restrict__ of, const int* __restrict__ ix,
              float* __restrict__ out, int E, int D, int G, int B) {
  const int rsub = threadIdx.x >> 7;        // 0..1 (row within pair)
  const int t = threadIdx.x & 127;          // float4 index within row (D/4 = 128)
  const long nrows = (long)B * E;
  for (long row = (long)blockIdx.x * 2 + rsub; row < nrows; row += (long)gridDim.x * 2) {
    int b = (int)(row / E);
    int e = (int)(row - (long)b * E);
    int g = ix[e];
    const float4* src = reinterpret_cast<const float4*>(of + ((size_t)b * G + g) * D);
    float4* dst = reinterpret_cast<float4*>(out + (size_t)row * D);
    dst[t] = src[t];
  }
}

extern "C" void kernel_launch(void* const* d_in, const int* in_sizes, int n_in,
                              void* d_out, int out_size, void* d_ws, size_t ws_size,
                              hipStream_t stream) {
  const float* x   = (const float*)d_in[0];
  const int*   ix  = (const int*)d_in[1];
  const float* Wf  = (const float*)d_in[2];
  const float* bfb = (const float*)d_in[3];
  const float* Wg  = (const float*)d_in[4];
  const float* bg  = (const float*)d_in[5];
  const float* Wh  = (const float*)d_in[6];
  const float* bh  = (const float*)d_in[7];

  const int E = in_sizes[1];
  const int D = in_sizes[3];
  const int B = in_sizes[0] / (E * D);
  const int G = NUM_GROUPS_C;
  const int M = B * E;
  const long xn = (long)M * D;

  char* ws = (char*)d_ws;
  size_t off = 0;
  auto alloc = [&](size_t bytes) -> char* {
    char* p = ws + off;
    off += (bytes + 255) & ~(size_t)255;
    return p;
  };
  u16* xb  = (u16*)alloc((size_t)M * D * 2);
  u16* lgb = (u16*)alloc((size_t)M * D * 2);
  u16* vlb = (u16*)alloc((size_t)M * D * 2);
  u16* Wgb = (u16*)alloc((size_t)D * D * 2);
  u16* Wfb = (u16*)alloc((size_t)D * D * 2);
  u16* Whb = (u16*)alloc((size_t)D * D * 2);
  u16* yb  = (u16*)alloc((size_t)B * G * D * 2);
  float* ofb = (float*)alloc((size_t)B * G * D * 4);
  int* cnt    = (int*)alloc((size_t)G * 4);
  int* offs   = (int*)alloc((size_t)G * 4);
  int* cursor = (int*)alloc((size_t)G * 4);
  int* elist  = (int*)alloc((size_t)E * 4);

  // 1) casts to bf16
  cast_f32_bf16<<<2048, 256, 0, stream>>>(x, xb, xn / 4);
  dim3 gw(64, 3);
  cast_w3<<<gw, 256, 0, stream>>>(Wg, Wf, Wh, Wgb, Wfb, Whb, D * D / 4);

  // 2) bucket edges by group
  zero_i32<<<(G + 255) / 256, 256, 0, stream>>>(cnt, G);
  count_k<<<(E + 255) / 256, 256, 0, stream>>>(ix, cnt, E);
  scan_k<<<1, 256, 0, stream>>>(cnt, offs, cursor, G);
  scatter_k<<<(E + 255) / 256, 256, 0, stream>>>(ix, cursor, elist, E);

  // 3) fused f/g projections, R10 4-phase schedule at 16 waves; (M/256)*4 blocks
  gemm256_w16<<<(M / 256) * 4, 1024, 0, stream>>>(xb, Wgb, Wfb, bg, bfb, lgb, vlb, D, D);

  // 4) group-wise softmax + weighted sum -> y (B,G,D) bf16
  seg_softmax<<<G * B, 256, 0, stream>>>(lgb, vlb, cnt, offs, elist, yb, E, D, B, G);

  // 5) h projection: (B*G, D) x (D, D) -> fp32
  dim3 gh((B * G) / 128, D / 128);
  gemm_bf16_nt_f32out<<<gh, 256, 0, stream>>>(yb, Whb, bh, ofb, D, D);

  // 6) gather to output (fp32), grid-stride
  gather_k<<<2048, 256, 0, stream>>>(ofb, ix, (float*)d_out, E, D, G, B);
}

// Round 15
// 223.641 us; speedup vs baseline: 1.1489x; 1.1489x over previous
//
#include <hip/hip_runtime.h>
#include <hip/hip_bf16.h>
#include <cstdint>
#include <cstddef>

typedef __bf16 bf16x8 __attribute__((ext_vector_type(8)));
typedef float f32x4 __attribute__((ext_vector_type(4)));
using u16 = unsigned short;

#define NUM_GROUPS_C 2048

__device__ __forceinline__ u16 f2bf(float f) {
  union { float f; uint32_t u; } c; c.f = f;
  uint32_t r = (c.u + 0x7fffu + ((c.u >> 16) & 1u)) >> 16;
  return (u16)r;
}
__device__ __forceinline__ float bf2f(u16 h) {
  union { uint32_t u; float f; } c; c.u = ((uint32_t)h) << 16; return c.f;
}

__device__ __forceinline__ void glds16(const u16* g, void* l) {
  __builtin_amdgcn_global_load_lds((const __attribute__((address_space(1))) void*)g,
                                   (__attribute__((address_space(3))) void*)l, 16, 0, 0);
}

// ---------------- cast fp32 -> bf16, vectorized ----------------
__global__ void cast_f32_bf16(const float* __restrict__ src, u16* __restrict__ dst, long n4) {
  long i = (long)blockIdx.x * blockDim.x + threadIdx.x;
  long stride = (long)gridDim.x * blockDim.x;
  for (; i < n4; i += stride) {
    float4 v = reinterpret_cast<const float4*>(src)[i];
    uint2 o;
    o.x = (uint32_t)f2bf(v.x) | ((uint32_t)f2bf(v.y) << 16);
    o.y = (uint32_t)f2bf(v.z) | ((uint32_t)f2bf(v.w) << 16);
    reinterpret_cast<uint2*>(dst)[i] = o;
  }
}

// ---------------- cast 3 weight matrices fp32 -> bf16 (one launch) ----------------
__global__ void cast_w3(const float* __restrict__ w0, const float* __restrict__ w1,
                        const float* __restrict__ w2,
                        u16* __restrict__ o0, u16* __restrict__ o1, u16* __restrict__ o2,
                        int n4) {
  const float* src = (blockIdx.y == 0) ? w0 : (blockIdx.y == 1) ? w1 : w2;
  u16* dst = (blockIdx.y == 0) ? o0 : (blockIdx.y == 1) ? o1 : o2;
  int i = blockIdx.x * blockDim.x + threadIdx.x;
  int stride = gridDim.x * blockDim.x;
  for (; i < n4; i += stride) {
    float4 v = reinterpret_cast<const float4*>(src)[i];
    uint2 o;
    o.x = (uint32_t)f2bf(v.x) | ((uint32_t)f2bf(v.y) << 16);
    o.y = (uint32_t)f2bf(v.z) | ((uint32_t)f2bf(v.w) << 16);
    reinterpret_cast<uint2*>(dst)[i] = o;
  }
}

// ---------------- bucket edges by group ----------------
__global__ void zero_i32(int* p, int n) {
  int i = blockIdx.x * blockDim.x + threadIdx.x;
  if (i < n) p[i] = 0;
}
__global__ void count_k(const int* __restrict__ ix, int* __restrict__ cnt, int E) {
  int e = blockIdx.x * blockDim.x + threadIdx.x;
  if (e < E) atomicAdd(&cnt[ix[e]], 1);
}
__global__ void scan_k(const int* __restrict__ cnt, int* __restrict__ offs,
                       int* __restrict__ cursor, int G) {
  __shared__ int part[256];
  int t = threadIdx.x;
  int gpt = G / 256;
  int base = t * gpt;
  int loc[8];
  int s = 0;
  for (int j = 0; j < gpt; ++j) { loc[j] = cnt[base + j]; s += loc[j]; }
  part[t] = s;
  __syncthreads();
  for (int off = 1; off < 256; off <<= 1) {
    int v = (t >= off) ? part[t - off] : 0;
    __syncthreads();
    part[t] += v;
    __syncthreads();
  }
  int run = part[t] - s;
  for (int j = 0; j < gpt; ++j) {
    offs[base + j] = run;
    cursor[base + j] = run;
    run += loc[j];
  }
}
__global__ void scatter_k(const int* __restrict__ ix, int* __restrict__ cursor,
                          int* __restrict__ elist, int E) {
  int e = blockIdx.x * blockDim.x + threadIdx.x;
  if (e < E) {
    int g = ix[e];
    int pos = atomicAdd(&cursor[g], 1);
    elist[pos] = e;
  }
}

// ============ f/g GEMM: R10's 4-phase schedule (best measured: ~103 us, 660 TF) ============
// FINAL. Structural alternatives tried and rejected: free-flow (R3), gray-code phased (R3),
// in-GEMM fp32 cast (R8, -65 us), fine 4-phase w/o lead (R10, kept), 1-phase lead (R11,
// null), 2-tile deep pipeline (R12, L2 thrash), 16 waves (R14, -26 us). See R10 comments
// for phase map + vmcnt queue algebra; prologue vmcnt(4)+barrier is the R9 race fix.
__global__ __launch_bounds__(512, 2)
void gemm256_fg8(const u16* __restrict__ A,
                 const u16* __restrict__ B0g, const u16* __restrict__ B1g,
                 const float* __restrict__ bias0, const float* __restrict__ bias1,
                 u16* __restrict__ C0, u16* __restrict__ C1,
                 int K, int N) {
  __shared__ u16 lds[65536];   // 2 bufs x (A 32KB + B 32KB) = 128 KiB

  const int tid  = threadIdx.x;
  const int lane = tid & 63;
  const int wid  = tid >> 6;
  const int wm   = wid >> 2;   // 0..1
  const int wn   = wid & 3;    // 0..3
  const int fr   = lane & 15;
  const int fq   = lane >> 4;
  const int swr  = fr & 7;     // read-side swizzle key (all frag rows ≡ fr mod 8)

  // bijective XCD swizzle; ns fastest within mt for A-panel L2 reuse
  const int nwg = gridDim.x, cpx = nwg >> 3, wg = blockIdx.x;
  const int swz = (wg & 7) * cpx + (wg >> 3);
  const int mt = swz >> 2, ns = swz & 3;
  const u16* Bm     = (ns < 2) ? B0g : B1g;
  const float* bias = (ns < 2) ? bias0 : bias1;
  u16* C            = (ns < 2) ? C0 : C1;
  const int n0 = (ns & 1) * 256, m0 = mt * 256;

  const int r8   = tid >> 3;
  const int scol = ((tid & 7) ^ (r8 & 7)) << 3;
  const u16* Ab = A  + (size_t)m0 * K + scol;
  const u16* Bb = Bm + (size_t)n0 * K + scol;
  char* ldsb = (char*)lds;

  auto stage_ht = [&](int p, int isB, int h, int kt) {
    const u16* src = (isB ? Bb : Ab) + (size_t)(h * 128 + r8) * K + kt * 64;
    char* dst = ldsb + p * 65536 + isB * 32768 + h * 16384 + wid * 1024;
    glds16(src, dst);
    glds16(src + (size_t)64 * K, dst + 8192);
  };

#define RD_A(dst, mi_, kk_) \
  dst = *(const bf16x8*)(sA_ + (((mi_) * 32 + wm * 16 + fr) << 7) + (((((kk_) << 2) | fq) ^ swr) << 4))
#define RD_B(dst, nj_, kk_) \
  dst = *(const bf16x8*)(sB_ + (((nj_) * 64 + wn * 16 + fr) << 7) + (((((kk_) << 2) | fq) ^ swr) << 4))
#define MFMA_Q(accm, accn, af, bf_)                                                \
  __builtin_amdgcn_s_setprio(1);                                                  \
  _Pragma("unroll") for (int j = 0; j < 4; ++j)                                    \
  _Pragma("unroll") for (int jn = 0; jn < 2; ++jn)                                 \
  _Pragma("unroll") for (int kk = 0; kk < 2; ++kk)                                 \
    acc[(accm) + j][(accn) + jn] = __builtin_amdgcn_mfma_f32_16x16x32_bf16(        \
        af[j][kk], bf_[jn][kk], acc[(accm) + j][(accn) + jn], 0, 0, 0);            \
  __builtin_amdgcn_s_setprio(0);

  f32x4 acc[8][4] = {};
  const int NT = K >> 6;

  // prologue: K-tile 0 halves, order [B0, A0, B1, A1], into buf 0
  stage_ht(0, 1, 0, 0);
  stage_ht(0, 0, 0, 0);
  stage_ht(0, 1, 1, 0);
  stage_ht(0, 0, 1, 0);
  // retire B0(0), A0(0) (phase 0's reads) before entering the loop
  asm volatile("s_waitcnt vmcnt(4)" ::: "memory");
  __builtin_amdgcn_s_barrier();

  for (int kt = 0; kt < NT; ++kt) {
    const int cb = kt & 1, nb = cb ^ 1;
    const int ks = (kt + 1 < NT) ? kt + 1 : NT - 1;  // tail: redundant restage (dead buffer)
    const char* sA_ = ldsb + cb * 65536;
    const char* sB_ = sA_ + 32768;
    bf16x8 a0[4][2], a1[4][2], b0[2][2], b1[2][2];

    // ---- phase 0: read A-half0 + B-half0, MFMA quadrant (0,0) ----
    #pragma unroll
    for (int j = 0; j < 4; ++j) { RD_A(a0[j][0], j, 0); RD_A(a0[j][1], j, 1); }
    #pragma unroll
    for (int j = 0; j < 2; ++j) { RD_B(b0[j][0], j, 0); RD_B(b0[j][1], j, 1); }
    stage_ht(nb, 1, 0, ks);                              // B0(kt+1)
    asm volatile("s_waitcnt vmcnt(4)" ::: "memory");
    __builtin_amdgcn_s_barrier();
    MFMA_Q(0, 0, a0, b0)
    __builtin_amdgcn_s_barrier();

    // ---- phase 1: read B-half1, MFMA (0,1) ----
    #pragma unroll
    for (int j = 0; j < 2; ++j) { RD_B(b1[j][0], j + 2, 0); RD_B(b1[j][1], j + 2, 1); }
    stage_ht(nb, 0, 0, ks);                              // A0(kt+1)
    asm volatile("s_waitcnt vmcnt(4)" ::: "memory");
    __builtin_amdgcn_s_barrier();
    MFMA_Q(0, 2, a0, b1)
    __builtin_amdgcn_s_barrier();

    // ---- phase 2: read A-half1, MFMA (1,1) ----
    #pragma unroll
    for (int j = 0; j < 4; ++j) { RD_A(a1[j][0], j + 4, 0); RD_A(a1[j][1], j + 4, 1); }
    stage_ht(nb, 1, 1, ks);                              // B1(kt+1)
    asm volatile("s_waitcnt vmcnt(4)" ::: "memory");
    __builtin_amdgcn_s_barrier();
    MFMA_Q(4, 2, a1, b1)
    __builtin_amdgcn_s_barrier();

    // ---- phase 3: no LDS reads, MFMA (1,0) ----
    stage_ht(nb, 0, 1, ks);                              // A1(kt+1)
    asm volatile("s_waitcnt vmcnt(4)" ::: "memory");
    __builtin_amdgcn_s_barrier();
    MFMA_Q(4, 0, a1, b0)
    __builtin_amdgcn_s_barrier();
  }
  asm volatile("s_waitcnt vmcnt(0)" ::: "memory");       // retire tail restage DMA

  // epilogue: C/D layout col=lane&15, row=(lane>>4)*4+r; interleaved frag mapping
  #pragma unroll
  for (int mi = 0; mi < 8; ++mi) {
    const int row = m0 + mi * 32 + wm * 16 + fq * 4;
    #pragma unroll
    for (int ni = 0; ni < 4; ++ni) {
      const int col = n0 + ni * 64 + wn * 16 + fr;
      const float bvv = bias[col];
      #pragma unroll
      for (int r = 0; r < 4; ++r)
        C[(size_t)(row + r) * N + col] = f2bf(acc[mi][ni][r] + bvv);
    }
  }
#undef RD_A
#undef RD_B
#undef MFMA_Q
}

// ---------------- 128x128 m97-structure GEMM (small h projection) ----------------
__device__ __forceinline__ void stage_tile_128x64(const u16* __restrict__ src, int ld,
                                                  u16* lds, int tid) {
  int wid = tid >> 6;
  #pragma unroll
  for (int i = 0; i < 4; ++i) {
    int c = i * 256 + tid;
    const u16* g = src + (size_t)(c >> 3) * ld + ((c & 7) << 3);
    char* l = (char*)lds + ((i * 4 + wid) << 10);
    glds16(g, l);
  }
}

__global__ __launch_bounds__(256)
void gemm_bf16_nt_f32out(const u16* __restrict__ A, const u16* __restrict__ Bm,
                         const float* __restrict__ bias,
                         float* __restrict__ C, int K, int N) {
  __shared__ u16 sA[128 * 64];
  __shared__ u16 sB[128 * 64];

  int tid = threadIdx.x;
  const int m0 = blockIdx.x * 128, n0 = blockIdx.y * 128;
  const u16* Ap = A + (size_t)m0 * K;
  const u16* Bp = Bm + (size_t)n0 * K;

  int lane = tid & 63;
  int wid = tid >> 6;
  int wm = wid >> 1, wn = wid & 1;
  int fr = lane & 15;
  int fq = lane >> 4;

  f32x4 acc[4][4] = {};

  for (int k0 = 0; k0 < K; k0 += 64) {
    stage_tile_128x64(Ap + k0, K, sA, tid);
    stage_tile_128x64(Bp + k0, K, sB, tid);
    __syncthreads();
    #pragma unroll
    for (int kk = 0; kk < 2; ++kk) {
      bf16x8 af[4], bfrag[4];
      #pragma unroll
      for (int mi = 0; mi < 4; ++mi)
        af[mi] = *reinterpret_cast<const bf16x8*>(&sA[(wm * 64 + mi * 16 + fr) * 64 + kk * 32 + fq * 8]);
      #pragma unroll
      for (int nj = 0; nj < 4; ++nj)
        bfrag[nj] = *reinterpret_cast<const bf16x8*>(&sB[(wn * 64 + nj * 16 + fr) * 64 + kk * 32 + fq * 8]);
      #pragma unroll
      for (int mi = 0; mi < 4; ++mi)
        #pragma unroll
        for (int nj = 0; nj < 4; ++nj)
          acc[mi][nj] = __builtin_amdgcn_mfma_f32_16x16x32_bf16(af[mi], bfrag[nj], acc[mi][nj], 0, 0, 0);
    }
    __syncthreads();
  }

  #pragma unroll
  for (int nj = 0; nj < 4; ++nj) {
    int col = n0 + wn * 64 + nj * 16 + fr;
    float bv = bias[col];
    #pragma unroll
    for (int mi = 0; mi < 4; ++mi) {
      int rowb = m0 + wm * 64 + mi * 16 + fq * 4;
      #pragma unroll
      for (int r = 0; r < 4; ++r)
        C[(size_t)(rowb + r) * N + col] = acc[mi][nj][r] + bv;
    }
  }
}

// ---------------- group-wise online softmax + weighted sum ----------------
__global__ __launch_bounds__(256)
void seg_softmax(const u16* __restrict__ lg, const u16* __restrict__ vl,
                 const int* __restrict__ cnt, const int* __restrict__ offs,
                 const int* __restrict__ elist,
                 u16* __restrict__ y, int E, int D, int B, int G) {
  __shared__ int eids[256];
  int g = blockIdx.x / B;
  int b = blockIdx.x - g * B;
  int t = threadIdx.x;
  int n = cnt[g], start = offs[g];
  int d0 = t * 2;

  float m0 = -1e30f, m1 = -1e30f, s0 = 0.f, s1 = 0.f, a0 = 0.f, a1 = 0.f;
  for (int c0 = 0; c0 < n; c0 += 256) {
    int nc = n - c0; if (nc > 256) nc = 256;
    __syncthreads();
    if (t < nc) eids[t] = elist[start + c0 + t];
    __syncthreads();
    for (int i = 0; i < nc; ++i) {
      size_t base = ((size_t)b * E + eids[i]) * D + d0;
      uint32_t lu = *reinterpret_cast<const uint32_t*>(lg + base);
      uint32_t vu = *reinterpret_cast<const uint32_t*>(vl + base);
      float l0 = bf2f((u16)(lu & 0xffffu)), l1 = bf2f((u16)(lu >> 16));
      float v0 = bf2f((u16)(vu & 0xffffu)), v1 = bf2f((u16)(vu >> 16));
      float nm0 = fmaxf(m0, l0);
      float sc0 = __expf(m0 - nm0), w0 = __expf(l0 - nm0);
      s0 = s0 * sc0 + w0; a0 = a0 * sc0 + w0 * v0; m0 = nm0;
      float nm1 = fmaxf(m1, l1);
      float sc1 = __expf(m1 - nm1), w1 = __expf(l1 - nm1);
      s1 = s1 * sc1 + w1; a1 = a1 * sc1 + w1 * v1; m1 = nm1;
    }
  }
  float r0 = (n > 0) ? a0 / s0 : 0.f;
  float r1 = (n > 0) ? a1 / s1 : 0.f;
  size_t yoff = ((size_t)b * G + g) * D + d0;
  uint32_t o = (uint32_t)f2bf(r0) | ((uint32_t)f2bf(r1) << 16);
  *reinterpret_cast<uint32_t*>(y + yoff) = o;
}

// ---------------- gather rows back to edges (fp32 out), grid-stride ----------------
__global__ __launch_bounds__(256)
void gather_k(const float* __restrict__ of, const int* __restrict__ ix,
              float* __restrict__ out, int E, int D, int G, int B) {
  const int rsub = threadIdx.x >> 7;        // 0..1 (row within pair)
  const int t = threadIdx.x & 127;          // float4 index within row (D/4 = 128)
  const long nrows = (long)B * E;
  for (long row = (long)blockIdx.x * 2 + rsub; row < nrows; row += (long)gridDim.x * 2) {
    int b = (int)(row / E);
    int e = (int)(row - (long)b * E);
    int g = ix[e];
    const float4* src = reinterpret_cast<const float4*>(of + ((size_t)b * G + g) * D);
    float4* dst = reinterpret_cast<float4*>(out + (size_t)row * D);
    dst[t] = src[t];
  }
}

extern "C" void kernel_launch(void* const* d_in, const int* in_sizes, int n_in,
                              void* d_out, int out_size, void* d_ws, size_t ws_size,
                              hipStream_t stream) {
  const float* x   = (const float*)d_in[0];
  const int*   ix  = (const int*)d_in[1];
  const float* Wf  = (const float*)d_in[2];
  const float* bfb = (const float*)d_in[3];
  const float* Wg  = (const float*)d_in[4];
  const float* bg  = (const float*)d_in[5];
  const float* Wh  = (const float*)d_in[6];
  const float* bh  = (const float*)d_in[7];

  const int E = in_sizes[1];
  const int D = in_sizes[3];
  const int B = in_sizes[0] / (E * D);
  const int G = NUM_GROUPS_C;
  const int M = B * E;
  const long xn = (long)M * D;

  char* ws = (char*)d_ws;
  size_t off = 0;
  auto alloc = [&](size_t bytes) -> char* {
    char* p = ws + off;
    off += (bytes + 255) & ~(size_t)255;
    return p;
  };
  u16* xb  = (u16*)alloc((size_t)M * D * 2);
  u16* lgb = (u16*)alloc((size_t)M * D * 2);
  u16* vlb = (u16*)alloc((size_t)M * D * 2);
  u16* Wgb = (u16*)alloc((size_t)D * D * 2);
  u16* Wfb = (u16*)alloc((size_t)D * D * 2);
  u16* Whb = (u16*)alloc((size_t)D * D * 2);
  u16* yb  = (u16*)alloc((size_t)B * G * D * 2);
  float* ofb = (float*)alloc((size_t)B * G * D * 4);
  int* cnt    = (int*)alloc((size_t)G * 4);
  int* offs   = (int*)alloc((size_t)G * 4);
  int* cursor = (int*)alloc((size_t)G * 4);
  int* elist  = (int*)alloc((size_t)E * 4);

  // 1) casts to bf16
  cast_f32_bf16<<<2048, 256, 0, stream>>>(x, xb, xn / 4);
  dim3 gw(64, 3);
  cast_w3<<<gw, 256, 0, stream>>>(Wg, Wf, Wh, Wgb, Wfb, Whb, D * D / 4);

  // 2) bucket edges by group
  zero_i32<<<(G + 255) / 256, 256, 0, stream>>>(cnt, G);
  count_k<<<(E + 255) / 256, 256, 0, stream>>>(ix, cnt, E);
  scan_k<<<1, 256, 0, stream>>>(cnt, offs, cursor, G);
  scatter_k<<<(E + 255) / 256, 256, 0, stream>>>(ix, cursor, elist, E);

  // 3) fused f/g projections, R10 4-phase schedule (best measured); (M/256)*4 blocks
  gemm256_fg8<<<(M / 256) * 4, 512, 0, stream>>>(xb, Wgb, Wfb, bg, bfb, lgb, vlb, D, D);

  // 4) group-wise softmax + weighted sum -> y (B,G,D) bf16
  seg_softmax<<<G * B, 256, 0, stream>>>(lgb, vlb, cnt, offs, elist, yb, E, D, B, G);

  // 5) h projection: (B*G, D) x (D, D) -> fp32
  dim3 gh((B * G) / 128, D / 128);
  gemm_bf16_nt_f32out<<<gh, 256, 0, stream>>>(yb, Whb, bh, ofb, D, D);

  // 6) gather to output (fp32), grid-stride
  gather_k<<<2048, 256, 0, stream>>>(ofb, ix, (float*)d_out, E, D, G, B);
}